// Round 4
// baseline (192.890 us; speedup 1.0000x reference)
//
#include <hip/hip_runtime.h>

typedef unsigned short u16;
typedef unsigned int u32;
typedef __bf16 bf16x8 __attribute__((ext_vector_type(8)));
typedef float f32x4 __attribute__((ext_vector_type(4)));
typedef u16 u16x8 __attribute__((ext_vector_type(8)));

__device__ __forceinline__ u16 f2bf(float f) {
    __bf16 h = (__bf16)f;
    return __builtin_bit_cast(u16, h);
}
__device__ __forceinline__ float bf2f(u16 u) {
    unsigned int x = ((unsigned int)u) << 16;
    return __builtin_bit_cast(float, x);
}

union FragU { u16x8 u; bf16x8 v; };

// ---------------- workspace layout (float offsets) ----------------
constexpr size_t WB2F  = 0;        // frw2 bf16 [tap][och][cin]
constexpr size_t WB3F  = 18432;    // frw3
constexpr size_t WBV2  = 36864;    // vrw2
constexpr size_t W1T   = 55296;    // mw1 rows 1..64, [col][row-1]
constexpr size_t W2T   = 57344;    // mw2 transposed [j2][j1]
constexpr size_t X1    = 59392;    // 4*2016*64 u16 (ch-last bf16)
constexpr size_t FEATBF= 575488;
constexpr size_t NVOFF = 833536;   // [(b*7+v)*2+s][1024]
constexpr size_t CFOFF = 862208;

// ================= D1: feature conv1 (3->64) + weight prep ================
__global__ __launch_bounds__(256) void conv1feat_kernel(
    const float* __restrict__ in0, const float* __restrict__ in1,
    const float* __restrict__ in2,
    const float* __restrict__ wts, const float* __restrict__ bias,
    u16* __restrict__ out,
    const float* __restrict__ frw2, const float* __restrict__ frw3,
    const float* __restrict__ vrw2,
    const float* __restrict__ mw1, const float* __restrict__ mw2,
    u16* __restrict__ wb2, u16* __restrict__ wb3, u16* __restrict__ wbv,
    u16* __restrict__ w1t, u16* __restrict__ w2t)
{
    constexpr int W = 63, NPX = 2016, H = 32;
    const int t = threadIdx.x;
    if (blockIdx.z == 4) {
        const int tid = (blockIdx.y * 8 + blockIdx.x) * 256 + t;
        for (int i = tid; i < 36864; i += 16384) {
            int tap = i >> 12, och = (i >> 6) & 63, cin = i & 63;
            size_t s = (size_t)och * 576 + cin * 9 + tap;
            wb2[i] = f2bf(frw2[s]);
            wb3[i] = f2bf(frw3[s]);
            wbv[i] = f2bf(vrw2[s]);
        }
        for (int i = tid; i < 4096; i += 16384) {
            int col = i >> 6, r = i & 63;
            w1t[i] = f2bf(mw1[(1 + r) * 64 + col]);
            w2t[i] = f2bf(mw2[r * 64 + col]);
        }
        return;
    }
    const int px = blockIdx.y * 256 + t;
    const int m = blockIdx.z;
    const int og = blockIdx.x;
    if (px >= NPX) return;
    const int y = px / W, x = px - y * W;

    float acc[8];
#pragma unroll
    for (int oc = 0; oc < 8; ++oc) acc[oc] = bias[og * 8 + oc];

#pragma unroll
    for (int cin = 0; cin < 3; ++cin) {
        const float* ip = (cin == 0 ? in0 : (cin == 1 ? in1 : in2)) + (size_t)m * NPX;
        float tap[9];
#pragma unroll
        for (int dy = 0; dy < 3; ++dy) {
            int yy = y + dy - 1;
            bool ry = (yy >= 0) && (yy < H);
#pragma unroll
            for (int dx = 0; dx < 3; ++dx) {
                int xx = x + dx - 1;
                tap[dy * 3 + dx] = (ry && xx >= 0 && xx < W) ? ip[yy * W + xx] : 0.f;
            }
        }
#pragma unroll
        for (int oc = 0; oc < 8; ++oc) {
            const float* wr = wts + (size_t)(og * 8 + oc) * 27 + cin * 9;
#pragma unroll
            for (int j = 0; j < 9; ++j) acc[oc] = fmaf(tap[j], wr[j], acc[oc]);
        }
    }
    u16x8 pk;
#pragma unroll
    for (int oc = 0; oc < 8; ++oc) pk[oc] = f2bf(fmaxf(acc[oc], 0.f));
    *(u16x8*)(out + ((size_t)m * NPX + px) * 64 + og * 8) = pk;
}

// ================= fused feature conv2+conv3 (64->64->64) ==================
// grid (32, 4): one conv3 output row (63 px) per block; conv2 rows
// y0-1..y0+1 staged in swizzled LDS (halo recompute, no cross-block dep).
// MFMA fragment math / accumulate order copied verbatim from the verified
// convmfma_kernel -> bit-identical numerics.
__global__ __launch_bounds__(512) void feat23_kernel(
    const u16* __restrict__ x1, const u16* __restrict__ wb2,
    const float* __restrict__ frb2, const u16* __restrict__ wb3,
    const float* __restrict__ frb3, u16* __restrict__ featout)
{
    __shared__ __align__(16) u16 g2_s[192 * 64];   // 24576 B, swizzled

    const int t = threadIdx.x;
    const int y0 = blockIdx.x;          // 0..31 output row
    const int m  = blockIdx.y;          // 0..3
    const int w = t >> 6, lane = t & 63, q = lane >> 4, l15 = lane & 15;
    const u16* im = x1 + (size_t)m * 2016 * 64;

    // ---- phase 1: conv2 for rows y0-1..y0+1 (189 px) into g2_s ------------
#pragma unroll
    for (int i = 0; i < 6; ++i) {
        const int task = w + i * 8;          // 0..47
        const int tile = task >> 2, qb = task & 3;
        const int och  = qb * 16 + l15;
        const int pl2  = tile * 16 + l15;    // local px 0..191 (189 valid)
        const int ly   = pl2 / 63;
        const int x    = pl2 - ly * 63;
        const int gy   = y0 - 1 + ly;
        const bool pok = (pl2 < 189) && (gy >= 0) && (gy < 32);
        const int pg   = gy * 63 + x;

        f32x4 acc = f32x4{0.f, 0.f, 0.f, 0.f};
#pragma unroll
        for (int tap = 0; tap < 9; ++tap) {
            const int dy = tap / 3 - 1, dx = tap % 3 - 1;
            const bool valid = pok && (gy + dy >= 0) && (gy + dy < 32)
                                   && (x + dx >= 0) && (x + dx < 63);
            const u16* ap = im + (size_t)(pg + dy * 63 + dx) * 64;
            FragU a0, a1;
            if (valid) {
                a0 = *(const FragU*)(ap + q * 8);
                a1 = *(const FragU*)(ap + 32 + q * 8);
            } else {
#pragma unroll
                for (int jj = 0; jj < 8; ++jj) { a0.u[jj] = 0; a1.u[jj] = 0; }
            }
            const u16* bp = wb2 + tap * 4096 + och * 64;
            FragU b0 = *(const FragU*)(bp + q * 8);
            FragU b1 = *(const FragU*)(bp + 32 + q * 8);
            acc = __builtin_amdgcn_mfma_f32_16x16x32_bf16(a0.v, b0.v, acc, 0, 0, 0);
            acc = __builtin_amdgcn_mfma_f32_16x16x32_bf16(a1.v, b1.v, acc, 0, 0, 0);
        }

        const float bb = frb2[och];
#pragma unroll
        for (int e = 0; e < 4; ++e) {
            const int po  = tile * 16 + q * 4 + e;
            const int lyo = po / 63;
            const int gyo = y0 - 1 + lyo;
            float vv = (po < 189 && gyo >= 0 && gyo < 32) ? fmaxf(acc[e] + bb, 0.f) : 0.f;
            int byte = (po * 128 + och * 2) ^ ((po & 7) << 4);
            *(u16*)((char*)g2_s + byte) = f2bf(vv);
        }
    }
    __syncthreads();

    // ---- phase 2: conv3 for row y0 (63 px) from LDS -----------------------
#pragma unroll
    for (int i = 0; i < 2; ++i) {
        const int task = w + i * 8;          // 0..15
        const int tile = task >> 2, qb = task & 3;
        const int och  = qb * 16 + l15;
        const int pl3r = tile * 16 + l15;    // 0..63
        const int x    = (pl3r < 63) ? pl3r : 0;   // clamp pad lane

        f32x4 acc = f32x4{0.f, 0.f, 0.f, 0.f};
#pragma unroll
        for (int tap = 0; tap < 9; ++tap) {
            const int dy = tap / 3 - 1, dx = tap % 3 - 1;
            const int xx = x + dx;
            FragU a0, a1;
            if (xx >= 0 && xx < 63) {
                const int pl2s = (1 + dy) * 63 + xx;   // g2 local px
                int byte = (pl2s * 128 + q * 16) ^ ((pl2s & 7) << 4);
                a0 = *(const FragU*)((const char*)g2_s + byte);
                byte = (pl2s * 128 + 64 + q * 16) ^ ((pl2s & 7) << 4);
                a1 = *(const FragU*)((const char*)g2_s + byte);
            } else {
#pragma unroll
                for (int jj = 0; jj < 8; ++jj) { a0.u[jj] = 0; a1.u[jj] = 0; }
            }
            const u16* bp = wb3 + tap * 4096 + och * 64;
            FragU b0 = *(const FragU*)(bp + q * 8);
            FragU b1 = *(const FragU*)(bp + 32 + q * 8);
            acc = __builtin_amdgcn_mfma_f32_16x16x32_bf16(a0.v, b0.v, acc, 0, 0, 0);
            acc = __builtin_amdgcn_mfma_f32_16x16x32_bf16(a1.v, b1.v, acc, 0, 0, 0);
        }

        const float bb = frb3[och];
#pragma unroll
        for (int e = 0; e < 4; ++e) {
            const int po = tile * 16 + q * 4 + e;
            if (po < 63)
                featout[((size_t)m * 2016 + y0 * 63 + po) * 64 + och] =
                    f2bf(fmaxf(acc[e] + bb, 0.f));
        }
    }
}

// ================= MLP (r9/r10-verified single kernel) =====================
__global__ __launch_bounds__(256, 2) void mlp_mfma_kernel(
    const float* __restrict__ lf, const float* __restrict__ flow,
    const u16* __restrict__ feat,   // [bs][2016][64] bf16
    const u16* __restrict__ w1t, const u16* __restrict__ w2t,
    const float* __restrict__ w1, const float* __restrict__ b1,
    const float* __restrict__ b2,
    const float* __restrict__ w3, const float* __restrict__ b3g,
    const float* __restrict__ cw, const float* __restrict__ cbg,
    float* __restrict__ nv_out, float* __restrict__ cf_out)
{
    constexpr int SBS = 72;
    __shared__ __align__(16) float s_vec[7 * 64];
    __shared__ __align__(16) float s_flow[256];
    __shared__ __align__(16) float s_epi[256];
    __shared__ __align__(16) u16 s_base[256 * SBS];

    const int t = threadIdx.x;
    const int blk = blockIdx.x;
    const int bs = blk >> 7;
    const int n0 = (blk & 127) * 8;
    const int b = bs >> 1, s = bs & 1;
    const int w = t >> 6, lane = t & 63, q = lane >> 4, l15 = lane & 15;

    if (t < 64) {
        s_vec[t]       = b1[t];
        s_vec[64 + t]  = b2[t];
        s_vec[128 + t] = w3[t];
        s_vec[192 + t] = cw[t];
        s_vec[256 + t] = w1[t];            // row 0: flow weight
        s_vec[320 + t] = w1[65 * 64 + t];  // row 65: spatial
        s_vec[384 + t] = w1[66 * 64 + t];  // row 66: ang
    }
    {
        int nl = t >> 5, k = t & 31;
        int n = n0 + nl;
        int a = (bs * 32 + (n >> 5)) * 63 + (n & 31) + k;
        s_flow[t] = flow[a];
        s_epi[t]  = lf[a];
    }
    __syncthreads();

    const float b3s = b3g[0];
    const float cbs = cbg[0];

    FragU w1b[2][4];
#pragma unroll
    for (int ks = 0; ks < 2; ++ks)
#pragma unroll
        for (int nt = 0; nt < 4; ++nt)
            w1b[ks][nt] = *(const FragU*)(w1t + (nt * 16 + l15) * 64 + ks * 32 + q * 8);

    float w1r0pl[4], w1r65pl[4], b1pl[4];
#pragma unroll
    for (int nt = 0; nt < 4; ++nt) {
        int j1 = nt * 16 + l15;
        w1r0pl[nt]  = s_vec[256 + j1];
        w1r65pl[nt] = s_vec[320 + j1];
        b1pl[nt]    = s_vec[j1];
    }

#pragma unroll
    for (int mt = 0; mt < 4; ++mt) {
        const int rbase = w * 64 + mt * 16;
        FragU af[2];
        {
            int r = rbase + l15;
            int n = n0 + (r >> 5);
            int pos = (n >> 5) * 63 + (n & 31) + (r & 31);
            const u16* fp = feat + ((size_t)bs * 2016 + pos) * 64;
            af[0] = *(const FragU*)(fp + q * 8);
            af[1] = *(const FragU*)(fp + 32 + q * 8);
        }
        f32x4 flow4 = *(const f32x4*)(s_flow + rbase + q * 4);
#pragma unroll
        for (int nt = 0; nt < 4; ++nt) {
            f32x4 d = {0.f, 0.f, 0.f, 0.f};
            d = __builtin_amdgcn_mfma_f32_16x16x32_bf16(af[0].v, w1b[0][nt].v, d, 0, 0, 0);
            d = __builtin_amdgcn_mfma_f32_16x16x32_bf16(af[1].v, w1b[1][nt].v, d, 0, 0, 0);
#pragma unroll
            for (int e = 0; e < 4; ++e) {
                int r = rbase + q * 4 + e;
                int k = r & 31;
                float val = d[e] + flow4[e] * w1r0pl[nt]
                          + (float)(k - 16) * w1r65pl[nt] + b1pl[nt];
                s_base[r * SBS + nt * 16 + l15] = f2bf(val);
            }
        }
    }
    __syncthreads();

    FragU w2a[4][2];
#pragma unroll
    for (int mt = 0; mt < 4; ++mt)
#pragma unroll
        for (int ks = 0; ks < 2; ++ks)
            w2a[mt][ks] = *(const FragU*)(w2t + (mt * 16 + l15) * 64 + ks * 32 + q * 8);

    float w66pl[2][8];
#pragma unroll
    for (int ks = 0; ks < 2; ++ks)
#pragma unroll
        for (int jj = 0; jj < 8; ++jj)
            w66pl[ks][jj] = s_vec[384 + ks * 32 + q * 8 + jj];

    float b2pl[4][4], w3pl[4][4], cwpl[4][4];
#pragma unroll
    for (int mt = 0; mt < 4; ++mt)
#pragma unroll
        for (int e = 0; e < 4; ++e) {
            b2pl[mt][e] = s_vec[64 + mt * 16 + q * 4 + e];
            w3pl[mt][e] = s_vec[128 + mt * 16 + q * 4 + e];
            cwpl[mt][e] = s_vec[192 + mt * 16 + q * 4 + e];
        }
    float epi_pl[4];
#pragma unroll
    for (int nt = 0; nt < 4; ++nt) epi_pl[nt] = s_epi[w * 64 + nt * 16 + l15];

    for (int v = 0; v < 7; ++v) {
        float ang = (s == 0) ? -(float)(v + 1) : (float)(7 - v);
        f32x4 acc[4][4];
#pragma unroll
        for (int nt = 0; nt < 4; ++nt) {
            FragU bfr[2];
#pragma unroll
            for (int ks = 0; ks < 2; ++ks) {
                const u16x8 raw = *(const u16x8*)(s_base + (w * 64 + nt * 16 + l15) * SBS + ks * 32 + q * 8);
#pragma unroll
                for (int jj = 0; jj < 8; ++jj) {
                    float xv = bf2f(raw[jj]);
                    float hv = fmaxf(xv + ang * w66pl[ks][jj], 0.f);
                    bfr[ks].u[jj] = f2bf(hv);
                }
            }
#pragma unroll
            for (int mt = 0; mt < 4; ++mt) {
                f32x4 d = {0.f, 0.f, 0.f, 0.f};
                d = __builtin_amdgcn_mfma_f32_16x16x32_bf16(w2a[mt][0].v, bfr[0].v, d, 0, 0, 0);
                d = __builtin_amdgcn_mfma_f32_16x16x32_bf16(w2a[mt][1].v, bfr[1].v, d, 0, 0, 0);
                acc[mt][nt] = d;
            }
        }
        float wl[4], cfl[4];
#pragma unroll
        for (int nt = 0; nt < 4; ++nt) {
            float wls = 0.f, cfs = 0.f;
#pragma unroll
            for (int mt = 0; mt < 4; ++mt)
#pragma unroll
                for (int e = 0; e < 4; ++e) {
                    float h2 = fmaxf(acc[mt][nt][e] + b2pl[mt][e], 0.f);
                    wls += h2 * w3pl[mt][e];
                    cfs += h2 * cwpl[mt][e];
                }
            wls += __shfl_xor(wls, 16); wls += __shfl_xor(wls, 32);
            cfs += __shfl_xor(cfs, 16); cfs += __shfl_xor(cfs, 32);
            wl[nt]  = wls + b3s;
            cfl[nt] = cfs;
        }
#pragma unroll
        for (int ni = 0; ni < 2; ++ni) {
            float a0 = wl[ni * 2], a1 = wl[ni * 2 + 1];
            float mx = fmaxf(a0, a1);
#pragma unroll
            for (int msk = 1; msk <= 8; msk <<= 1) mx = fmaxf(mx, __shfl_xor(mx, msk));
            float e0 = __expf(a0 - mx), e1 = __expf(a1 - mx);
            float ssum = e0 + e1;
            float nvp = e0 * epi_pl[ni * 2] + e1 * epi_pl[ni * 2 + 1];
            float cfp = cfl[ni * 2] + cfl[ni * 2 + 1];
#pragma unroll
            for (int msk = 1; msk <= 8; msk <<= 1) {
                ssum += __shfl_xor(ssum, msk);
                nvp  += __shfl_xor(nvp, msk);
                cfp  += __shfl_xor(cfp, msk);
            }
            if (lane == 0) {
                int n = n0 + w * 2 + ni;
                size_t idx = ((size_t)(b * 7 + v) * 2 + s) * 1024 + n;
                nv_out[idx] = nvp / ssum;
                cf_out[idx] = cfp * (1.f / 32.f) + cbs;
            }
        }
    }
}

// ================= fused refine: conf-combine + conv1 + conv2 + conv3 ======
__global__ __launch_bounds__(512, 4) void refine_kernel(
    const float* __restrict__ nv, const float* __restrict__ cf,
    const float* __restrict__ pl, const float* __restrict__ pr,
    const float* __restrict__ vrw1, const float* __restrict__ vrb1,
    const u16* __restrict__ wbv, const float* __restrict__ vrb2,
    const float* __restrict__ vrw3, const float* __restrict__ vrb3,
    float* __restrict__ out)
{
    __shared__ __align__(16) float pn_s[10][32];        // pn rows y0-3..y0+6
    __shared__ __align__(16) float pls[10][32];         // patch_left rows (0 off-image)
    __shared__ __align__(16) float prs[10][32];         // patch_right rows
    __shared__ __align__(16) float sw3[576];            // vrw3 staged
    __shared__ __align__(16) u16 g1_s[8 * 32 * 64];     // conv1 out, rows y0-2..y0+5
    __shared__ __align__(16) u16 g2_s[6 * 32 * 64];     // conv2 out, rows y0-1..y0+4

    const int t = threadIdx.x;
    const int pt = blockIdx.x;          // 0..7  (4-row stripes)
    const int m  = blockIdx.y;          // 0..13
    const int y0 = pt * 4;

    // ---- phase A: conf-softmax combine into pn_s; stage pl/pr + vrw3 ------
    if (t < 320) {
        int rr = t >> 5, col = t & 31;
        int gy = y0 - 3 + rr;
        float vv = 0.f, vl = 0.f, vr = 0.f;
        if (gy >= 0 && gy < 32) {
            int n = gy * 32 + col;
            size_t i0 = ((size_t)m * 2) * 1024 + n;
            size_t i1 = i0 + 1024;
            float c0 = cf[i0], c1 = cf[i1];
            float mx = fmaxf(c0, c1);
            float e0 = __expf(c0 - mx), e1 = __expf(c1 - mx);
            vv = (e0 * nv[i0] + e1 * nv[i1]) / (e0 + e1);
            vl = pl[(size_t)m * 1024 + n];
            vr = pr[(size_t)m * 1024 + n];
        }
        pn_s[rr][col] = vv;
        pls[rr][col] = vl;
        prs[rr][col] = vr;
    }
    for (int i = t; i < 576; i += 512) sw3[i] = vrw3[i];
    __syncthreads();

    // ---- phase B: conv1 (3->64), wave-uniform weights (SGPR) --------------
    {
        const int wv = __builtin_amdgcn_readfirstlane(t >> 6);  // 0..7, uniform
        const int lane = t & 63;
        const int oh = wv & 1;                 // och half (uniform per wave)
        const int px_i = (wv >> 1) * 64 + lane;   // 0..255 over 8 g1 rows
        const int lr0 = px_i >> 5;             // g1 local row
        const int x = px_i & 31;
        const int gy = y0 - 2 + lr0;
        const bool inimg = (gy >= 0) && (gy < 32);

        float tap0[9], tap1[9], tap2[9];
#pragma unroll
        for (int dy = 0; dy < 3; ++dy) {
            const int prow = lr0 + dy;         // LDS row for yy = gy+dy-1
#pragma unroll
            for (int dx = 0; dx < 3; ++dx) {
                int xx = x + dx - 1;
                bool rx = (xx >= 0) && (xx < 32);
                tap0[dy * 3 + dx] = rx ? pn_s[prow][xx] : 0.f;
                tap1[dy * 3 + dx] = rx ? pls[prow][xx] : 0.f;
                tap2[dy * 3 + dx] = rx ? prs[prow][xx] : 0.f;
            }
        }
#pragma unroll
        for (int jg = 0; jg < 4; ++jg) {
            u16x8 pk;
#pragma unroll
            for (int e = 0; e < 8; ++e) {
                const int o = oh * 32 + jg * 8 + e;   // uniform per wave
                const float* wr = vrw1 + (size_t)o * 27;
                float acc = vrb1[o];
#pragma unroll
                for (int j = 0; j < 9; ++j) acc = fmaf(tap0[j], wr[j], acc);
#pragma unroll
                for (int j = 0; j < 9; ++j) acc = fmaf(tap1[j], wr[9 + j], acc);
#pragma unroll
                for (int j = 0; j < 9; ++j) acc = fmaf(tap2[j], wr[18 + j], acc);
                pk[e] = f2bf(inimg ? fmaxf(acc, 0.f) : 0.f);
            }
            int byte = (px_i * 128 + oh * 64 + jg * 16) ^ ((px_i & 7) << 4);
            *(u16x8*)((char*)g1_s + byte) = pk;
        }
    }
    __syncthreads();

    // ---- phase C: conv2 (64->64) via MFMA from LDS ------------------------
    {
        const int w = t >> 6, lane = t & 63, q = lane >> 4, l15 = lane & 15;
        const int ocht = w & 3, base = ocht * 16;
        const int wg = w >> 2;                // 0..1

        f32x4 acc[6];
#pragma unroll
        for (int i = 0; i < 6; ++i) acc[i] = f32x4{0.f, 0.f, 0.f, 0.f};

#pragma unroll
        for (int tap = 0; tap < 9; ++tap) {
            const int dy = tap / 3 - 1, dx = tap % 3 - 1;
            const u16* bp = wbv + tap * 4096 + (base + l15) * 64;
            FragU b0 = *(const FragU*)(bp + q * 8);
            FragU b1 = *(const FragU*)(bp + 32 + q * 8);
#pragma unroll
            for (int i = 0; i < 6; ++i) {
                const int p = (wg + 2 * i) * 16 + l15;     // g2 local px 0..191
                const int xx = (p & 31) + dx;
                const int p1 = p + (dy + 1) * 32 + dx;     // g1 local px
                FragU a0, a1;
                if (xx >= 0 && xx < 32) {
                    int byte = (p1 * 128 + q * 16) ^ ((p1 & 7) << 4);
                    a0 = *(const FragU*)((const char*)g1_s + byte);
                    byte = (p1 * 128 + 64 + q * 16) ^ ((p1 & 7) << 4);
                    a1 = *(const FragU*)((const char*)g1_s + byte);
                } else {
#pragma unroll
                    for (int jj = 0; jj < 8; ++jj) { a0.u[jj] = 0; a1.u[jj] = 0; }
                }
                acc[i] = __builtin_amdgcn_mfma_f32_16x16x32_bf16(a0.v, b0.v, acc[i], 0, 0, 0);
                acc[i] = __builtin_amdgcn_mfma_f32_16x16x32_bf16(a1.v, b1.v, acc[i], 0, 0, 0);
            }
        }

        const float bb = vrb2[base + l15];
#pragma unroll
        for (int i = 0; i < 6; ++i) {
#pragma unroll
            for (int e = 0; e < 4; ++e) {
                int p = (wg + 2 * i) * 16 + q * 4 + e;
                int gy2 = y0 - 1 + (p >> 5);
                float vv = (gy2 >= 0 && gy2 < 32) ? fmaxf(acc[i][e] + bb, 0.f) : 0.f;
                int byte = (p * 128 + (base + l15) * 2) ^ ((p & 7) << 4);
                *(u16*)((char*)g2_s + byte) = f2bf(vv);
            }
        }
    }
    __syncthreads();

    // ---- phase D: conv3 (64->1) + residual --------------------------------
    {
        const int px_i = t >> 2;              // 0..127 over 4 out rows
        const int part = t & 3;               // 16-och slice
        const int ly = px_i >> 5;
        const int x  = px_i & 31;

        float a = 0.f;
#pragma unroll
        for (int dy = 0; dy < 3; ++dy) {
#pragma unroll
            for (int dx = 0; dx < 3; ++dx) {
                int xx = x + dx - 1;
                if (xx < 0 || xx >= 32) continue;
                int p2 = px_i + dy * 32 + dx - 1;     // g2 local px
                const int tap = dy * 3 + dx;
                int byte0 = (p2 * 128 + part * 32) ^ ((p2 & 7) << 4);
                int byte1 = (p2 * 128 + part * 32 + 16) ^ ((p2 & 7) << 4);
                u16x8 r0 = *(const u16x8*)((const char*)g2_s + byte0);
                u16x8 r1 = *(const u16x8*)((const char*)g2_s + byte1);
#pragma unroll
                for (int e = 0; e < 8; ++e) {
                    a = fmaf(bf2f(r0[e]), sw3[(part * 16 + e) * 9 + tap], a);
                    a = fmaf(bf2f(r1[e]), sw3[(part * 16 + 8 + e) * 9 + tap], a);
                }
            }
        }
        a += __shfl_xor(a, 1);
        a += __shfl_xor(a, 2);
        if (part == 0) {
            int gy = y0 + ly;
            out[(size_t)m * 1024 + gy * 32 + x] = pn_s[ly + 3][x] + a + vrb3[0];
        }
    }
}

// ---------------- launch ----------------
extern "C" void kernel_launch(void* const* d_in, const int* in_sizes, int n_in,
                              void* d_out, int out_size, void* d_ws, size_t ws_size,
                              hipStream_t stream) {
    const float* lf   = (const float*)d_in[0];
    const float* flow = (const float*)d_in[1];
    const float* wp   = (const float*)d_in[2];
    const float* pl   = (const float*)d_in[3];
    const float* pr   = (const float*)d_in[4];
    float* ws = (float*)d_ws;

    conv1feat_kernel<<<dim3(8, 8, 5), 256, 0, stream>>>(
        flow, lf, wp, (const float*)d_in[5], (const float*)d_in[6],
        (u16*)(ws + X1),
        (const float*)d_in[7], (const float*)d_in[9], (const float*)d_in[21],
        (const float*)d_in[11], (const float*)d_in[13],
        (u16*)(ws + WB2F), (u16*)(ws + WB3F), (u16*)(ws + WBV2),
        (u16*)(ws + W1T), (u16*)(ws + W2T));

    feat23_kernel<<<dim3(32, 4), 512, 0, stream>>>(
        (const u16*)(ws + X1), (const u16*)(ws + WB2F), (const float*)d_in[8],
        (const u16*)(ws + WB3F), (const float*)d_in[10],
        (u16*)(ws + FEATBF));

    mlp_mfma_kernel<<<512, 256, 0, stream>>>(
        lf, flow, (const u16*)(ws + FEATBF),
        (const u16*)(ws + W1T), (const u16*)(ws + W2T),
        (const float*)d_in[11], (const float*)d_in[12],
        (const float*)d_in[14],
        (const float*)d_in[15], (const float*)d_in[16],
        (const float*)d_in[17], (const float*)d_in[18],
        ws + NVOFF, ws + CFOFF);

    refine_kernel<<<dim3(8, 14), 512, 0, stream>>>(
        ws + NVOFF, ws + CFOFF, pl, pr,
        (const float*)d_in[19], (const float*)d_in[20],
        (const u16*)(ws + WBV2), (const float*)d_in[22],
        (const float*)d_in[23], (const float*)d_in[24],
        (float*)d_out);
}

// Round 6
// 184.241 us; speedup vs baseline: 1.0469x; 1.0469x over previous
//
#include <hip/hip_runtime.h>

typedef unsigned short u16;
typedef unsigned int u32;
typedef __bf16 bf16x8 __attribute__((ext_vector_type(8)));
typedef float f32x4 __attribute__((ext_vector_type(4)));
typedef u16 u16x8 __attribute__((ext_vector_type(8)));

__device__ __forceinline__ u16 f2bf(float f) {
    __bf16 h = (__bf16)f;
    return __builtin_bit_cast(u16, h);
}
__device__ __forceinline__ float bf2f(u16 u) {
    unsigned int x = ((unsigned int)u) << 16;
    return __builtin_bit_cast(float, x);
}

union FragU { u16x8 u; bf16x8 v; };

// ---------------- workspace layout (float offsets) ----------------
constexpr size_t WB2F  = 0;        // frw2 bf16 [tap][och][cin]
constexpr size_t WB3F  = 18432;    // frw3
constexpr size_t WBV2  = 36864;    // vrw2
constexpr size_t W1T   = 55296;    // mw1 rows 1..64, [col][row-1]
constexpr size_t W2T   = 57344;    // mw2 transposed [j2][j1]
constexpr size_t X1    = 59392;    // 4*2016*64 u16 (ch-last bf16)
constexpr size_t X2    = 317440;
constexpr size_t FEATBF= 575488;
constexpr size_t NVOFF = 833536;   // [(b*7+v)*2+s][1024]
constexpr size_t CFOFF = 862208;

// ================= D1: feature conv1 (3->64) + weight prep ================
__global__ __launch_bounds__(256) void conv1feat_kernel(
    const float* __restrict__ in0, const float* __restrict__ in1,
    const float* __restrict__ in2,
    const float* __restrict__ wts, const float* __restrict__ bias,
    u16* __restrict__ out,
    const float* __restrict__ frw2, const float* __restrict__ frw3,
    const float* __restrict__ vrw2,
    const float* __restrict__ mw1, const float* __restrict__ mw2,
    u16* __restrict__ wb2, u16* __restrict__ wb3, u16* __restrict__ wbv,
    u16* __restrict__ w1t, u16* __restrict__ w2t)
{
    constexpr int W = 63, NPX = 2016, H = 32;
    const int t = threadIdx.x;
    if (blockIdx.z == 4) {
        const int tid = (blockIdx.y * 8 + blockIdx.x) * 256 + t;
        for (int i = tid; i < 36864; i += 16384) {
            int tap = i >> 12, och = (i >> 6) & 63, cin = i & 63;
            size_t s = (size_t)och * 576 + cin * 9 + tap;
            wb2[i] = f2bf(frw2[s]);
            wb3[i] = f2bf(frw3[s]);
            wbv[i] = f2bf(vrw2[s]);
        }
        for (int i = tid; i < 4096; i += 16384) {
            int col = i >> 6, r = i & 63;
            w1t[i] = f2bf(mw1[(1 + r) * 64 + col]);
            w2t[i] = f2bf(mw2[r * 64 + col]);
        }
        return;
    }
    const int px = blockIdx.y * 256 + t;
    const int m = blockIdx.z;
    const int og = blockIdx.x;
    if (px >= NPX) return;
    const int y = px / W, x = px - y * W;

    float acc[8];
#pragma unroll
    for (int oc = 0; oc < 8; ++oc) acc[oc] = bias[og * 8 + oc];

#pragma unroll
    for (int cin = 0; cin < 3; ++cin) {
        const float* ip = (cin == 0 ? in0 : (cin == 1 ? in1 : in2)) + (size_t)m * NPX;
        float tap[9];
#pragma unroll
        for (int dy = 0; dy < 3; ++dy) {
            int yy = y + dy - 1;
            bool ry = (yy >= 0) && (yy < H);
#pragma unroll
            for (int dx = 0; dx < 3; ++dx) {
                int xx = x + dx - 1;
                tap[dy * 3 + dx] = (ry && xx >= 0 && xx < W) ? ip[yy * W + xx] : 0.f;
            }
        }
#pragma unroll
        for (int oc = 0; oc < 8; ++oc) {
            const float* wr = wts + (size_t)(og * 8 + oc) * 27 + cin * 9;
#pragma unroll
            for (int j = 0; j < 9; ++j) acc[oc] = fmaf(tap[j], wr[j], acc[oc]);
        }
    }
    u16x8 pk;
#pragma unroll
    for (int oc = 0; oc < 8; ++oc) pk[oc] = f2bf(fmaxf(acc[oc], 0.f));
    *(u16x8*)(out + ((size_t)m * NPX + px) * 64 + og * 8) = pk;
}

// ================= convMFMA, och-split NT tiles (feature convs) ============
template<int W, int NPX, int NT>
__global__ __launch_bounds__(256) void convmfma_kernel(
    const u16* __restrict__ in, const u16* __restrict__ wbf,
    const float* __restrict__ bias, u16* __restrict__ out)
{
    constexpr int H = 32;
    const int t = threadIdx.x;
    const int base = blockIdx.x * 64;
    const int ochb = blockIdx.y * (NT * 16);
    const int m = blockIdx.z;
    const int w = t >> 6, lane = t & 63, q = lane >> 4, l15 = lane & 15;

    const u16* im = in + (size_t)m * NPX * 64;
    const int pxA = base + w * 16 + l15;
    const int yA = pxA / W, xA = pxA - yA * W;
    const bool pxok = (pxA < NPX);

    f32x4 acc[NT];
#pragma unroll
    for (int nt = 0; nt < NT; ++nt) acc[nt] = f32x4{0.f, 0.f, 0.f, 0.f};

#pragma unroll
    for (int tap = 0; tap < 9; ++tap) {
        const int dy = tap / 3 - 1, dx = tap % 3 - 1;
        const bool valid = pxok && (yA + dy >= 0) && (yA + dy < H)
                                && (xA + dx >= 0) && (xA + dx < W);
        const u16* ap = im + (size_t)(pxA + dy * W + dx) * 64;
        FragU a0, a1;
        if (valid) {
            a0 = *(const FragU*)(ap + q * 8);
            a1 = *(const FragU*)(ap + 32 + q * 8);
        } else {
#pragma unroll
            for (int jj = 0; jj < 8; ++jj) { a0.u[jj] = 0; a1.u[jj] = 0; }
        }
#pragma unroll
        for (int nt = 0; nt < NT; ++nt) {
            const u16* bp = wbf + tap * 4096 + (ochb + nt * 16 + l15) * 64;
            FragU b0 = *(const FragU*)(bp + q * 8);
            FragU b1 = *(const FragU*)(bp + 32 + q * 8);
            acc[nt] = __builtin_amdgcn_mfma_f32_16x16x32_bf16(a0.v, b0.v, acc[nt], 0, 0, 0);
            acc[nt] = __builtin_amdgcn_mfma_f32_16x16x32_bf16(a1.v, b1.v, acc[nt], 0, 0, 0);
        }
    }

#pragma unroll
    for (int nt = 0; nt < NT; ++nt) {
        const float bb = bias[ochb + nt * 16 + l15];
#pragma unroll
        for (int e = 0; e < 4; ++e) {
            int pxs = base + w * 16 + q * 4 + e;
            if (pxs < NPX)
                out[((size_t)m * NPX + pxs) * 64 + ochb + nt * 16 + l15] =
                    f2bf(fmaxf(acc[nt][e] + bb, 0.f));
        }
    }
}

// ================= MLP, view-split (r5) ====================================
// r5: the v-loop (relu+cvt VALU, ~5:1 VALU:MFMA) dominated; split 7 views
// across 2 blocks (v<4 / v>=4). h1-base phase duplicated (cheap: 8 MFMA).
// 1024 blocks x 40960B LDS = 4 blocks/CU (exactly 160KiB). Per-view math
// bit-identical to the verified kernel.
__global__ __launch_bounds__(256, 2) void mlp_mfma_kernel(
    const float* __restrict__ lf, const float* __restrict__ flow,
    const u16* __restrict__ feat,   // [bs][2016][64] bf16
    const u16* __restrict__ w1t, const u16* __restrict__ w2t,
    const float* __restrict__ w1, const float* __restrict__ b1,
    const float* __restrict__ b2,
    const float* __restrict__ w3, const float* __restrict__ b3g,
    const float* __restrict__ cw, const float* __restrict__ cbg,
    float* __restrict__ nv_out, float* __restrict__ cf_out)
{
    constexpr int SBS = 72;
    __shared__ __align__(16) float s_vec[7 * 64];
    __shared__ __align__(16) float s_flow[256];
    __shared__ __align__(16) float s_epi[256];
    __shared__ __align__(16) u16 s_base[256 * SBS];

    const int t = threadIdx.x;
    const int blk = blockIdx.x;
    const int vh = blk & 1;              // view half: v in [0,4) or [4,7)
    const int rest = blk >> 1;
    const int bs = rest >> 7;
    const int n0 = (rest & 127) * 8;
    const int b = bs >> 1, s = bs & 1;
    const int w = t >> 6, lane = t & 63, q = lane >> 4, l15 = lane & 15;

    if (t < 64) {
        s_vec[t]       = b1[t];
        s_vec[64 + t]  = b2[t];
        s_vec[128 + t] = w3[t];
        s_vec[192 + t] = cw[t];
        s_vec[256 + t] = w1[t];            // row 0: flow weight
        s_vec[320 + t] = w1[65 * 64 + t];  // row 65: spatial
        s_vec[384 + t] = w1[66 * 64 + t];  // row 66: ang
    }
    {
        int nl = t >> 5, k = t & 31;
        int n = n0 + nl;
        int a = (bs * 32 + (n >> 5)) * 63 + (n & 31) + k;
        s_flow[t] = flow[a];
        s_epi[t]  = lf[a];
    }
    __syncthreads();

    const float b3s = b3g[0];
    const float cbs = cbg[0];

    FragU w1b[2][4];
#pragma unroll
    for (int ks = 0; ks < 2; ++ks)
#pragma unroll
        for (int nt = 0; nt < 4; ++nt)
            w1b[ks][nt] = *(const FragU*)(w1t + (nt * 16 + l15) * 64 + ks * 32 + q * 8);

    float w1r0pl[4], w1r65pl[4], b1pl[4];
#pragma unroll
    for (int nt = 0; nt < 4; ++nt) {
        int j1 = nt * 16 + l15;
        w1r0pl[nt]  = s_vec[256 + j1];
        w1r65pl[nt] = s_vec[320 + j1];
        b1pl[nt]    = s_vec[j1];
    }

#pragma unroll
    for (int mt = 0; mt < 4; ++mt) {
        const int rbase = w * 64 + mt * 16;
        FragU af[2];
        {
            int r = rbase + l15;
            int n = n0 + (r >> 5);
            int pos = (n >> 5) * 63 + (n & 31) + (r & 31);
            const u16* fp = feat + ((size_t)bs * 2016 + pos) * 64;
            af[0] = *(const FragU*)(fp + q * 8);
            af[1] = *(const FragU*)(fp + 32 + q * 8);
        }
        f32x4 flow4 = *(const f32x4*)(s_flow + rbase + q * 4);
#pragma unroll
        for (int nt = 0; nt < 4; ++nt) {
            f32x4 d = {0.f, 0.f, 0.f, 0.f};
            d = __builtin_amdgcn_mfma_f32_16x16x32_bf16(af[0].v, w1b[0][nt].v, d, 0, 0, 0);
            d = __builtin_amdgcn_mfma_f32_16x16x32_bf16(af[1].v, w1b[1][nt].v, d, 0, 0, 0);
#pragma unroll
            for (int e = 0; e < 4; ++e) {
                int r = rbase + q * 4 + e;
                int k = r & 31;
                float val = d[e] + flow4[e] * w1r0pl[nt]
                          + (float)(k - 16) * w1r65pl[nt] + b1pl[nt];
                s_base[r * SBS + nt * 16 + l15] = f2bf(val);
            }
        }
    }
    __syncthreads();

    FragU w2a[4][2];
#pragma unroll
    for (int mt = 0; mt < 4; ++mt)
#pragma unroll
        for (int ks = 0; ks < 2; ++ks)
            w2a[mt][ks] = *(const FragU*)(w2t + (mt * 16 + l15) * 64 + ks * 32 + q * 8);

    float w66pl[2][8];
#pragma unroll
    for (int ks = 0; ks < 2; ++ks)
#pragma unroll
        for (int jj = 0; jj < 8; ++jj)
            w66pl[ks][jj] = s_vec[384 + ks * 32 + q * 8 + jj];

    float b2pl[4][4], w3pl[4][4], cwpl[4][4];
#pragma unroll
    for (int mt = 0; mt < 4; ++mt)
#pragma unroll
        for (int e = 0; e < 4; ++e) {
            b2pl[mt][e] = s_vec[64 + mt * 16 + q * 4 + e];
            w3pl[mt][e] = s_vec[128 + mt * 16 + q * 4 + e];
            cwpl[mt][e] = s_vec[192 + mt * 16 + q * 4 + e];
        }
    float epi_pl[4];
#pragma unroll
    for (int nt = 0; nt < 4; ++nt) epi_pl[nt] = s_epi[w * 64 + nt * 16 + l15];

    const int vend = vh ? 7 : 4;
    for (int v = vh * 4; v < vend; ++v) {
        float ang = (s == 0) ? -(float)(v + 1) : (float)(7 - v);
        f32x4 acc[4][4];
#pragma unroll
        for (int nt = 0; nt < 4; ++nt) {
            FragU bfr[2];
#pragma unroll
            for (int ks = 0; ks < 2; ++ks) {
                const u16x8 raw = *(const u16x8*)(s_base + (w * 64 + nt * 16 + l15) * SBS + ks * 32 + q * 8);
#pragma unroll
                for (int jj = 0; jj < 8; ++jj) {
                    float xv = bf2f(raw[jj]);
                    float hv = fmaxf(xv + ang * w66pl[ks][jj], 0.f);
                    bfr[ks].u[jj] = f2bf(hv);
                }
            }
#pragma unroll
            for (int mt = 0; mt < 4; ++mt) {
                f32x4 d = {0.f, 0.f, 0.f, 0.f};
                d = __builtin_amdgcn_mfma_f32_16x16x32_bf16(w2a[mt][0].v, bfr[0].v, d, 0, 0, 0);
                d = __builtin_amdgcn_mfma_f32_16x16x32_bf16(w2a[mt][1].v, bfr[1].v, d, 0, 0, 0);
                acc[mt][nt] = d;
            }
        }
        float wl[4], cfl[4];
#pragma unroll
        for (int nt = 0; nt < 4; ++nt) {
            float wls = 0.f, cfs = 0.f;
#pragma unroll
            for (int mt = 0; mt < 4; ++mt)
#pragma unroll
                for (int e = 0; e < 4; ++e) {
                    float h2 = fmaxf(acc[mt][nt][e] + b2pl[mt][e], 0.f);
                    wls += h2 * w3pl[mt][e];
                    cfs += h2 * cwpl[mt][e];
                }
            wls += __shfl_xor(wls, 16); wls += __shfl_xor(wls, 32);
            cfs += __shfl_xor(cfs, 16); cfs += __shfl_xor(cfs, 32);
            wl[nt]  = wls + b3s;
            cfl[nt] = cfs;
        }
#pragma unroll
        for (int ni = 0; ni < 2; ++ni) {
            float a0 = wl[ni * 2], a1 = wl[ni * 2 + 1];
            float mx = fmaxf(a0, a1);
#pragma unroll
            for (int msk = 1; msk <= 8; msk <<= 1) mx = fmaxf(mx, __shfl_xor(mx, msk));
            float e0 = __expf(a0 - mx), e1 = __expf(a1 - mx);
            float ssum = e0 + e1;
            float nvp = e0 * epi_pl[ni * 2] + e1 * epi_pl[ni * 2 + 1];
            float cfp = cfl[ni * 2] + cfl[ni * 2 + 1];
#pragma unroll
            for (int msk = 1; msk <= 8; msk <<= 1) {
                ssum += __shfl_xor(ssum, msk);
                nvp  += __shfl_xor(nvp, msk);
                cfp  += __shfl_xor(cfp, msk);
            }
            if (lane == 0) {
                int n = n0 + w * 2 + ni;
                size_t idx = ((size_t)(b * 7 + v) * 2 + s) * 1024 + n;
                nv_out[idx] = nvp / ssum;
                cf_out[idx] = cfp * (1.f / 32.f) + cbs;
            }
        }
    }
}

// ================= fused refine: conf-combine + conv1 + conv2 + conv3 ======
__global__ __launch_bounds__(512, 4) void refine_kernel(
    const float* __restrict__ nv, const float* __restrict__ cf,
    const float* __restrict__ pl, const float* __restrict__ pr,
    const float* __restrict__ vrw1, const float* __restrict__ vrb1,
    const u16* __restrict__ wbv, const float* __restrict__ vrb2,
    const float* __restrict__ vrw3, const float* __restrict__ vrb3,
    float* __restrict__ out)
{
    __shared__ __align__(16) float pn_s[10][32];        // pn rows y0-3..y0+6
    __shared__ __align__(16) float pls[10][32];         // patch_left rows (0 off-image)
    __shared__ __align__(16) float prs[10][32];         // patch_right rows
    __shared__ __align__(16) float sw3[576];            // vrw3 staged
    __shared__ __align__(16) u16 g1_s[8 * 32 * 64];     // conv1 out, rows y0-2..y0+5
    __shared__ __align__(16) u16 g2_s[6 * 32 * 64];     // conv2 out, rows y0-1..y0+4

    const int t = threadIdx.x;
    const int pt = blockIdx.x;          // 0..7  (4-row stripes)
    const int m  = blockIdx.y;          // 0..13
    const int y0 = pt * 4;

    // ---- phase A: conf-softmax combine into pn_s; stage pl/pr + vrw3 ------
    if (t < 320) {
        int rr = t >> 5, col = t & 31;
        int gy = y0 - 3 + rr;
        float vv = 0.f, vl = 0.f, vr = 0.f;
        if (gy >= 0 && gy < 32) {
            int n = gy * 32 + col;
            size_t i0 = ((size_t)m * 2) * 1024 + n;
            size_t i1 = i0 + 1024;
            float c0 = cf[i0], c1 = cf[i1];
            float mx = fmaxf(c0, c1);
            float e0 = __expf(c0 - mx), e1 = __expf(c1 - mx);
            vv = (e0 * nv[i0] + e1 * nv[i1]) / (e0 + e1);
            vl = pl[(size_t)m * 1024 + n];
            vr = pr[(size_t)m * 1024 + n];
        }
        pn_s[rr][col] = vv;
        pls[rr][col] = vl;
        prs[rr][col] = vr;
    }
    for (int i = t; i < 576; i += 512) sw3[i] = vrw3[i];
    __syncthreads();

    // ---- phase B: conv1 (3->64), wave-uniform weights (SGPR) --------------
    {
        const int wv = __builtin_amdgcn_readfirstlane(t >> 6);  // 0..7, uniform
        const int lane = t & 63;
        const int oh = wv & 1;                 // och half (uniform per wave)
        const int px_i = (wv >> 1) * 64 + lane;   // 0..255 over 8 g1 rows
        const int lr0 = px_i >> 5;             // g1 local row
        const int x = px_i & 31;
        const int gy = y0 - 2 + lr0;
        const bool inimg = (gy >= 0) && (gy < 32);

        float tap0[9], tap1[9], tap2[9];
#pragma unroll
        for (int dy = 0; dy < 3; ++dy) {
            const int prow = lr0 + dy;         // LDS row for yy = gy+dy-1
#pragma unroll
            for (int dx = 0; dx < 3; ++dx) {
                int xx = x + dx - 1;
                bool rx = (xx >= 0) && (xx < 32);
                tap0[dy * 3 + dx] = rx ? pn_s[prow][xx] : 0.f;
                tap1[dy * 3 + dx] = rx ? pls[prow][xx] : 0.f;
                tap2[dy * 3 + dx] = rx ? prs[prow][xx] : 0.f;
            }
        }
#pragma unroll
        for (int jg = 0; jg < 4; ++jg) {
            u16x8 pk;
#pragma unroll
            for (int e = 0; e < 8; ++e) {
                const int o = oh * 32 + jg * 8 + e;   // uniform per wave
                const float* wr = vrw1 + (size_t)o * 27;
                float acc = vrb1[o];
#pragma unroll
                for (int j = 0; j < 9; ++j) acc = fmaf(tap0[j], wr[j], acc);
#pragma unroll
                for (int j = 0; j < 9; ++j) acc = fmaf(tap1[j], wr[9 + j], acc);
#pragma unroll
                for (int j = 0; j < 9; ++j) acc = fmaf(tap2[j], wr[18 + j], acc);
                pk[e] = f2bf(inimg ? fmaxf(acc, 0.f) : 0.f);
            }
            int byte = (px_i * 128 + oh * 64 + jg * 16) ^ ((px_i & 7) << 4);
            *(u16x8*)((char*)g1_s + byte) = pk;
        }
    }
    __syncthreads();

    // ---- phase C: conv2 (64->64) via MFMA from LDS ------------------------
    {
        const int w = t >> 6, lane = t & 63, q = lane >> 4, l15 = lane & 15;
        const int ocht = w & 3, base = ocht * 16;
        const int wg = w >> 2;                // 0..1

        f32x4 acc[6];
#pragma unroll
        for (int i = 0; i < 6; ++i) acc[i] = f32x4{0.f, 0.f, 0.f, 0.f};

#pragma unroll
        for (int tap = 0; tap < 9; ++tap) {
            const int dy = tap / 3 - 1, dx = tap % 3 - 1;
            const u16* bp = wbv + tap * 4096 + (base + l15) * 64;
            FragU b0 = *(const FragU*)(bp + q * 8);
            FragU b1 = *(const FragU*)(bp + 32 + q * 8);
#pragma unroll
            for (int i = 0; i < 6; ++i) {
                const int p = (wg + 2 * i) * 16 + l15;     // g2 local px 0..191
                const int xx = (p & 31) + dx;
                const int p1 = p + (dy + 1) * 32 + dx;     // g1 local px
                FragU a0, a1;
                if (xx >= 0 && xx < 32) {
                    int byte = (p1 * 128 + q * 16) ^ ((p1 & 7) << 4);
                    a0 = *(const FragU*)((const char*)g1_s + byte);
                    byte = (p1 * 128 + 64 + q * 16) ^ ((p1 & 7) << 4);
                    a1 = *(const FragU*)((const char*)g1_s + byte);
                } else {
#pragma unroll
                    for (int jj = 0; jj < 8; ++jj) { a0.u[jj] = 0; a1.u[jj] = 0; }
                }
                acc[i] = __builtin_amdgcn_mfma_f32_16x16x32_bf16(a0.v, b0.v, acc[i], 0, 0, 0);
                acc[i] = __builtin_amdgcn_mfma_f32_16x16x32_bf16(a1.v, b1.v, acc[i], 0, 0, 0);
            }
        }

        const float bb = vrb2[base + l15];
#pragma unroll
        for (int i = 0; i < 6; ++i) {
#pragma unroll
            for (int e = 0; e < 4; ++e) {
                int p = (wg + 2 * i) * 16 + q * 4 + e;
                int gy2 = y0 - 1 + (p >> 5);
                float vv = (gy2 >= 0 && gy2 < 32) ? fmaxf(acc[i][e] + bb, 0.f) : 0.f;
                int byte = (p * 128 + (base + l15) * 2) ^ ((p & 7) << 4);
                *(u16*)((char*)g2_s + byte) = f2bf(vv);
            }
        }
    }
    __syncthreads();

    // ---- phase D: conv3 (64->1) + residual --------------------------------
    {
        const int px_i = t >> 2;              // 0..127 over 4 out rows
        const int part = t & 3;               // 16-och slice
        const int ly = px_i >> 5;
        const int x  = px_i & 31;

        float a = 0.f;
#pragma unroll
        for (int dy = 0; dy < 3; ++dy) {
#pragma unroll
            for (int dx = 0; dx < 3; ++dx) {
                int xx = x + dx - 1;
                if (xx < 0 || xx >= 32) continue;
                int p2 = px_i + dy * 32 + dx - 1;     // g2 local px
                const int tap = dy * 3 + dx;
                int byte0 = (p2 * 128 + part * 32) ^ ((p2 & 7) << 4);
                int byte1 = (p2 * 128 + part * 32 + 16) ^ ((p2 & 7) << 4);
                u16x8 r0 = *(const u16x8*)((const char*)g2_s + byte0);
                u16x8 r1 = *(const u16x8*)((const char*)g2_s + byte1);
#pragma unroll
                for (int e = 0; e < 8; ++e) {
                    a = fmaf(bf2f(r0[e]), sw3[(part * 16 + e) * 9 + tap], a);
                    a = fmaf(bf2f(r1[e]), sw3[(part * 16 + 8 + e) * 9 + tap], a);
                }
            }
        }
        a += __shfl_xor(a, 1);
        a += __shfl_xor(a, 2);
        if (part == 0) {
            int gy = y0 + ly;
            out[(size_t)m * 1024 + gy * 32 + x] = pn_s[ly + 3][x] + a + vrb3[0];
        }
    }
}

// ---------------- launch ----------------
extern "C" void kernel_launch(void* const* d_in, const int* in_sizes, int n_in,
                              void* d_out, int out_size, void* d_ws, size_t ws_size,
                              hipStream_t stream) {
    const float* lf   = (const float*)d_in[0];
    const float* flow = (const float*)d_in[1];
    const float* wp   = (const float*)d_in[2];
    const float* pl   = (const float*)d_in[3];
    const float* pr   = (const float*)d_in[4];
    float* ws = (float*)d_ws;

    conv1feat_kernel<<<dim3(8, 8, 5), 256, 0, stream>>>(
        flow, lf, wp, (const float*)d_in[5], (const float*)d_in[6],
        (u16*)(ws + X1),
        (const float*)d_in[7], (const float*)d_in[9], (const float*)d_in[21],
        (const float*)d_in[11], (const float*)d_in[13],
        (u16*)(ws + WB2F), (u16*)(ws + WB3F), (u16*)(ws + WBV2),
        (u16*)(ws + W1T), (u16*)(ws + W2T));

    convmfma_kernel<63, 2016, 1><<<dim3(32, 4, 4), 256, 0, stream>>>(
        (const u16*)(ws + X1), (const u16*)(ws + WB2F), (const float*)d_in[8],
        (u16*)(ws + X2));
    convmfma_kernel<63, 2016, 1><<<dim3(32, 4, 4), 256, 0, stream>>>(
        (const u16*)(ws + X2), (const u16*)(ws + WB3F), (const float*)d_in[10],
        (u16*)(ws + FEATBF));

    mlp_mfma_kernel<<<1024, 256, 0, stream>>>(
        lf, flow, (const u16*)(ws + FEATBF),
        (const u16*)(ws + W1T), (const u16*)(ws + W2T),
        (const float*)d_in[11], (const float*)d_in[12],
        (const float*)d_in[14],
        (const float*)d_in[15], (const float*)d_in[16],
        (const float*)d_in[17], (const float*)d_in[18],
        ws + NVOFF, ws + CFOFF);

    refine_kernel<<<dim3(8, 14), 512, 0, stream>>>(
        ws + NVOFF, ws + CFOFF, pl, pr,
        (const float*)d_in[19], (const float*)d_in[20],
        (const u16*)(ws + WBV2), (const float*)d_in[22],
        (const float*)d_in[23], (const float*)d_in[24],
        (float*)d_out);
}

// Round 7
// 180.087 us; speedup vs baseline: 1.0711x; 1.0231x over previous
//
#include <hip/hip_runtime.h>

typedef unsigned short u16;
typedef unsigned int u32;
typedef __bf16 bf16x8 __attribute__((ext_vector_type(8)));
typedef float f32x4 __attribute__((ext_vector_type(4)));
typedef u16 u16x8 __attribute__((ext_vector_type(8)));

__device__ __forceinline__ u16 f2bf(float f) {
    __bf16 h = (__bf16)f;
    return __builtin_bit_cast(u16, h);
}
__device__ __forceinline__ float bf2f(u16 u) {
    unsigned int x = ((unsigned int)u) << 16;
    return __builtin_bit_cast(float, x);
}

union FragU { u16x8 u; bf16x8 v; };

// ---------------- workspace layout (float offsets) ----------------
constexpr size_t WB2F  = 0;        // frw2 bf16 [tap][och][cin]
constexpr size_t WB3F  = 18432;    // frw3
constexpr size_t WBV2  = 36864;    // vrw2
constexpr size_t W1T   = 55296;    // mw1 rows 1..64, [col][row-1]
constexpr size_t W2T   = 57344;    // mw2 transposed [j2][j1]
constexpr size_t X1    = 59392;    // 4*2016*64 u16 (ch-last bf16)
constexpr size_t X2    = 317440;
constexpr size_t FEATBF= 575488;
constexpr size_t NVOFF = 833536;   // [(b*7+v)*2+s][1024]
constexpr size_t CFOFF = 862208;

// ================= D1: feature conv1 (3->64) + weight prep ================
__global__ __launch_bounds__(256) void conv1feat_kernel(
    const float* __restrict__ in0, const float* __restrict__ in1,
    const float* __restrict__ in2,
    const float* __restrict__ wts, const float* __restrict__ bias,
    u16* __restrict__ out,
    const float* __restrict__ frw2, const float* __restrict__ frw3,
    const float* __restrict__ vrw2,
    const float* __restrict__ mw1, const float* __restrict__ mw2,
    u16* __restrict__ wb2, u16* __restrict__ wb3, u16* __restrict__ wbv,
    u16* __restrict__ w1t, u16* __restrict__ w2t)
{
    constexpr int W = 63, NPX = 2016, H = 32;
    const int t = threadIdx.x;
    if (blockIdx.z == 4) {
        const int tid = (blockIdx.y * 8 + blockIdx.x) * 256 + t;
        for (int i = tid; i < 36864; i += 16384) {
            int tap = i >> 12, och = (i >> 6) & 63, cin = i & 63;
            size_t s = (size_t)och * 576 + cin * 9 + tap;
            wb2[i] = f2bf(frw2[s]);
            wb3[i] = f2bf(frw3[s]);
            wbv[i] = f2bf(vrw2[s]);
        }
        for (int i = tid; i < 4096; i += 16384) {
            int col = i >> 6, r = i & 63;
            w1t[i] = f2bf(mw1[(1 + r) * 64 + col]);
            w2t[i] = f2bf(mw2[r * 64 + col]);
        }
        return;
    }
    const int px = blockIdx.y * 256 + t;
    const int m = blockIdx.z;
    const int og = blockIdx.x;
    if (px >= NPX) return;
    const int y = px / W, x = px - y * W;

    float acc[8];
#pragma unroll
    for (int oc = 0; oc < 8; ++oc) acc[oc] = bias[og * 8 + oc];

#pragma unroll
    for (int cin = 0; cin < 3; ++cin) {
        const float* ip = (cin == 0 ? in0 : (cin == 1 ? in1 : in2)) + (size_t)m * NPX;
        float tap[9];
#pragma unroll
        for (int dy = 0; dy < 3; ++dy) {
            int yy = y + dy - 1;
            bool ry = (yy >= 0) && (yy < H);
#pragma unroll
            for (int dx = 0; dx < 3; ++dx) {
                int xx = x + dx - 1;
                tap[dy * 3 + dx] = (ry && xx >= 0 && xx < W) ? ip[yy * W + xx] : 0.f;
            }
        }
#pragma unroll
        for (int oc = 0; oc < 8; ++oc) {
            const float* wr = wts + (size_t)(og * 8 + oc) * 27 + cin * 9;
#pragma unroll
            for (int j = 0; j < 9; ++j) acc[oc] = fmaf(tap[j], wr[j], acc[oc]);
        }
    }
    u16x8 pk;
#pragma unroll
    for (int oc = 0; oc < 8; ++oc) pk[oc] = f2bf(fmaxf(acc[oc], 0.f));
    *(u16x8*)(out + ((size_t)m * NPX + px) * 64 + og * 8) = pk;
}

// ================= convMFMA, och-split NT tiles (feature convs) ============
template<int W, int NPX, int NT>
__global__ __launch_bounds__(256) void convmfma_kernel(
    const u16* __restrict__ in, const u16* __restrict__ wbf,
    const float* __restrict__ bias, u16* __restrict__ out)
{
    constexpr int H = 32;
    const int t = threadIdx.x;
    const int base = blockIdx.x * 64;
    const int ochb = blockIdx.y * (NT * 16);
    const int m = blockIdx.z;
    const int w = t >> 6, lane = t & 63, q = lane >> 4, l15 = lane & 15;

    const u16* im = in + (size_t)m * NPX * 64;
    const int pxA = base + w * 16 + l15;
    const int yA = pxA / W, xA = pxA - yA * W;
    const bool pxok = (pxA < NPX);

    f32x4 acc[NT];
#pragma unroll
    for (int nt = 0; nt < NT; ++nt) acc[nt] = f32x4{0.f, 0.f, 0.f, 0.f};

#pragma unroll
    for (int tap = 0; tap < 9; ++tap) {
        const int dy = tap / 3 - 1, dx = tap % 3 - 1;
        const bool valid = pxok && (yA + dy >= 0) && (yA + dy < H)
                                && (xA + dx >= 0) && (xA + dx < W);
        const u16* ap = im + (size_t)(pxA + dy * W + dx) * 64;
        FragU a0, a1;
        if (valid) {
            a0 = *(const FragU*)(ap + q * 8);
            a1 = *(const FragU*)(ap + 32 + q * 8);
        } else {
#pragma unroll
            for (int jj = 0; jj < 8; ++jj) { a0.u[jj] = 0; a1.u[jj] = 0; }
        }
#pragma unroll
        for (int nt = 0; nt < NT; ++nt) {
            const u16* bp = wbf + tap * 4096 + (ochb + nt * 16 + l15) * 64;
            FragU b0 = *(const FragU*)(bp + q * 8);
            FragU b1 = *(const FragU*)(bp + 32 + q * 8);
            acc[nt] = __builtin_amdgcn_mfma_f32_16x16x32_bf16(a0.v, b0.v, acc[nt], 0, 0, 0);
            acc[nt] = __builtin_amdgcn_mfma_f32_16x16x32_bf16(a1.v, b1.v, acc[nt], 0, 0, 0);
        }
    }

#pragma unroll
    for (int nt = 0; nt < NT; ++nt) {
        const float bb = bias[ochb + nt * 16 + l15];
#pragma unroll
        for (int e = 0; e < 4; ++e) {
            int pxs = base + w * 16 + q * 4 + e;
            if (pxs < NPX)
                out[((size_t)m * NPX + pxs) * 64 + ochb + nt * 16 + l15] =
                    f2bf(fmaxf(acc[nt][e] + bb, 0.f));
        }
    }
}

// ================= MLP (r9/r10-verified single kernel) =====================
__global__ __launch_bounds__(256, 2) void mlp_mfma_kernel(
    const float* __restrict__ lf, const float* __restrict__ flow,
    const u16* __restrict__ feat,   // [bs][2016][64] bf16
    const u16* __restrict__ w1t, const u16* __restrict__ w2t,
    const float* __restrict__ w1, const float* __restrict__ b1,
    const float* __restrict__ b2,
    const float* __restrict__ w3, const float* __restrict__ b3g,
    const float* __restrict__ cw, const float* __restrict__ cbg,
    float* __restrict__ nv_out, float* __restrict__ cf_out)
{
    constexpr int SBS = 72;
    __shared__ __align__(16) float s_vec[7 * 64];
    __shared__ __align__(16) float s_flow[256];
    __shared__ __align__(16) float s_epi[256];
    __shared__ __align__(16) u16 s_base[256 * SBS];

    const int t = threadIdx.x;
    const int blk = blockIdx.x;
    const int bs = blk >> 7;
    const int n0 = (blk & 127) * 8;
    const int b = bs >> 1, s = bs & 1;
    const int w = t >> 6, lane = t & 63, q = lane >> 4, l15 = lane & 15;

    if (t < 64) {
        s_vec[t]       = b1[t];
        s_vec[64 + t]  = b2[t];
        s_vec[128 + t] = w3[t];
        s_vec[192 + t] = cw[t];
        s_vec[256 + t] = w1[t];            // row 0: flow weight
        s_vec[320 + t] = w1[65 * 64 + t];  // row 65: spatial
        s_vec[384 + t] = w1[66 * 64 + t];  // row 66: ang
    }
    {
        int nl = t >> 5, k = t & 31;
        int n = n0 + nl;
        int a = (bs * 32 + (n >> 5)) * 63 + (n & 31) + k;
        s_flow[t] = flow[a];
        s_epi[t]  = lf[a];
    }
    __syncthreads();

    const float b3s = b3g[0];
    const float cbs = cbg[0];

    FragU w1b[2][4];
#pragma unroll
    for (int ks = 0; ks < 2; ++ks)
#pragma unroll
        for (int nt = 0; nt < 4; ++nt)
            w1b[ks][nt] = *(const FragU*)(w1t + (nt * 16 + l15) * 64 + ks * 32 + q * 8);

    float w1r0pl[4], w1r65pl[4], b1pl[4];
#pragma unroll
    for (int nt = 0; nt < 4; ++nt) {
        int j1 = nt * 16 + l15;
        w1r0pl[nt]  = s_vec[256 + j1];
        w1r65pl[nt] = s_vec[320 + j1];
        b1pl[nt]    = s_vec[j1];
    }

#pragma unroll
    for (int mt = 0; mt < 4; ++mt) {
        const int rbase = w * 64 + mt * 16;
        FragU af[2];
        {
            int r = rbase + l15;
            int n = n0 + (r >> 5);
            int pos = (n >> 5) * 63 + (n & 31) + (r & 31);
            const u16* fp = feat + ((size_t)bs * 2016 + pos) * 64;
            af[0] = *(const FragU*)(fp + q * 8);
            af[1] = *(const FragU*)(fp + 32 + q * 8);
        }
        f32x4 flow4 = *(const f32x4*)(s_flow + rbase + q * 4);
#pragma unroll
        for (int nt = 0; nt < 4; ++nt) {
            f32x4 d = {0.f, 0.f, 0.f, 0.f};
            d = __builtin_amdgcn_mfma_f32_16x16x32_bf16(af[0].v, w1b[0][nt].v, d, 0, 0, 0);
            d = __builtin_amdgcn_mfma_f32_16x16x32_bf16(af[1].v, w1b[1][nt].v, d, 0, 0, 0);
#pragma unroll
            for (int e = 0; e < 4; ++e) {
                int r = rbase + q * 4 + e;
                int k = r & 31;
                float val = d[e] + flow4[e] * w1r0pl[nt]
                          + (float)(k - 16) * w1r65pl[nt] + b1pl[nt];
                s_base[r * SBS + nt * 16 + l15] = f2bf(val);
            }
        }
    }
    __syncthreads();

    FragU w2a[4][2];
#pragma unroll
    for (int mt = 0; mt < 4; ++mt)
#pragma unroll
        for (int ks = 0; ks < 2; ++ks)
            w2a[mt][ks] = *(const FragU*)(w2t + (mt * 16 + l15) * 64 + ks * 32 + q * 8);

    float w66pl[2][8];
#pragma unroll
    for (int ks = 0; ks < 2; ++ks)
#pragma unroll
        for (int jj = 0; jj < 8; ++jj)
            w66pl[ks][jj] = s_vec[384 + ks * 32 + q * 8 + jj];

    float b2pl[4][4], w3pl[4][4], cwpl[4][4];
#pragma unroll
    for (int mt = 0; mt < 4; ++mt)
#pragma unroll
        for (int e = 0; e < 4; ++e) {
            b2pl[mt][e] = s_vec[64 + mt * 16 + q * 4 + e];
            w3pl[mt][e] = s_vec[128 + mt * 16 + q * 4 + e];
            cwpl[mt][e] = s_vec[192 + mt * 16 + q * 4 + e];
        }
    float epi_pl[4];
#pragma unroll
    for (int nt = 0; nt < 4; ++nt) epi_pl[nt] = s_epi[w * 64 + nt * 16 + l15];

    for (int v = 0; v < 7; ++v) {
        float ang = (s == 0) ? -(float)(v + 1) : (float)(7 - v);
        f32x4 acc[4][4];
#pragma unroll
        for (int nt = 0; nt < 4; ++nt) {
            FragU bfr[2];
#pragma unroll
            for (int ks = 0; ks < 2; ++ks) {
                const u16x8 raw = *(const u16x8*)(s_base + (w * 64 + nt * 16 + l15) * SBS + ks * 32 + q * 8);
#pragma unroll
                for (int jj = 0; jj < 8; ++jj) {
                    float xv = bf2f(raw[jj]);
                    float hv = fmaxf(xv + ang * w66pl[ks][jj], 0.f);
                    bfr[ks].u[jj] = f2bf(hv);
                }
            }
#pragma unroll
            for (int mt = 0; mt < 4; ++mt) {
                f32x4 d = {0.f, 0.f, 0.f, 0.f};
                d = __builtin_amdgcn_mfma_f32_16x16x32_bf16(w2a[mt][0].v, bfr[0].v, d, 0, 0, 0);
                d = __builtin_amdgcn_mfma_f32_16x16x32_bf16(w2a[mt][1].v, bfr[1].v, d, 0, 0, 0);
                acc[mt][nt] = d;
            }
        }
        float wl[4], cfl[4];
#pragma unroll
        for (int nt = 0; nt < 4; ++nt) {
            float wls = 0.f, cfs = 0.f;
#pragma unroll
            for (int mt = 0; mt < 4; ++mt)
#pragma unroll
                for (int e = 0; e < 4; ++e) {
                    float h2 = fmaxf(acc[mt][nt][e] + b2pl[mt][e], 0.f);
                    wls += h2 * w3pl[mt][e];
                    cfs += h2 * cwpl[mt][e];
                }
            wls += __shfl_xor(wls, 16); wls += __shfl_xor(wls, 32);
            cfs += __shfl_xor(cfs, 16); cfs += __shfl_xor(cfs, 32);
            wl[nt]  = wls + b3s;
            cfl[nt] = cfs;
        }
#pragma unroll
        for (int ni = 0; ni < 2; ++ni) {
            float a0 = wl[ni * 2], a1 = wl[ni * 2 + 1];
            float mx = fmaxf(a0, a1);
#pragma unroll
            for (int msk = 1; msk <= 8; msk <<= 1) mx = fmaxf(mx, __shfl_xor(mx, msk));
            float e0 = __expf(a0 - mx), e1 = __expf(a1 - mx);
            float ssum = e0 + e1;
            float nvp = e0 * epi_pl[ni * 2] + e1 * epi_pl[ni * 2 + 1];
            float cfp = cfl[ni * 2] + cfl[ni * 2 + 1];
#pragma unroll
            for (int msk = 1; msk <= 8; msk <<= 1) {
                ssum += __shfl_xor(ssum, msk);
                nvp  += __shfl_xor(nvp, msk);
                cfp  += __shfl_xor(cfp, msk);
            }
            if (lane == 0) {
                int n = n0 + w * 2 + ni;
                size_t idx = ((size_t)(b * 7 + v) * 2 + s) * 1024 + n;
                nv_out[idx] = nvp / ssum;
                cf_out[idx] = cfp * (1.f / 32.f) + cbs;
            }
        }
    }
}

// ================= fused refine: conf-combine + conv1 + conv2 + conv3 ======
__global__ __launch_bounds__(512, 4) void refine_kernel(
    const float* __restrict__ nv, const float* __restrict__ cf,
    const float* __restrict__ pl, const float* __restrict__ pr,
    const float* __restrict__ vrw1, const float* __restrict__ vrb1,
    const u16* __restrict__ wbv, const float* __restrict__ vrb2,
    const float* __restrict__ vrw3, const float* __restrict__ vrb3,
    float* __restrict__ out)
{
    __shared__ __align__(16) float pn_s[10][32];        // pn rows y0-3..y0+6
    __shared__ __align__(16) float pls[10][32];         // patch_left rows (0 off-image)
    __shared__ __align__(16) float prs[10][32];         // patch_right rows
    __shared__ __align__(16) float sw3[576];            // vrw3 staged
    __shared__ __align__(16) u16 g1_s[8 * 32 * 64];     // conv1 out, rows y0-2..y0+5
    __shared__ __align__(16) u16 g2_s[6 * 32 * 64];     // conv2 out, rows y0-1..y0+4

    const int t = threadIdx.x;
    const int pt = blockIdx.x;          // 0..7  (4-row stripes)
    const int m  = blockIdx.y;          // 0..13
    const int y0 = pt * 4;

    // ---- phase A: conf-softmax combine into pn_s; stage pl/pr + vrw3 ------
    if (t < 320) {
        int rr = t >> 5, col = t & 31;
        int gy = y0 - 3 + rr;
        float vv = 0.f, vl = 0.f, vr = 0.f;
        if (gy >= 0 && gy < 32) {
            int n = gy * 32 + col;
            size_t i0 = ((size_t)m * 2) * 1024 + n;
            size_t i1 = i0 + 1024;
            float c0 = cf[i0], c1 = cf[i1];
            float mx = fmaxf(c0, c1);
            float e0 = __expf(c0 - mx), e1 = __expf(c1 - mx);
            vv = (e0 * nv[i0] + e1 * nv[i1]) / (e0 + e1);
            vl = pl[(size_t)m * 1024 + n];
            vr = pr[(size_t)m * 1024 + n];
        }
        pn_s[rr][col] = vv;
        pls[rr][col] = vl;
        prs[rr][col] = vr;
    }
    for (int i = t; i < 576; i += 512) sw3[i] = vrw3[i];
    __syncthreads();

    // ---- phase B: conv1 (3->64), wave-uniform weights (SGPR) --------------
    {
        const int wv = __builtin_amdgcn_readfirstlane(t >> 6);  // 0..7, uniform
        const int lane = t & 63;
        const int oh = wv & 1;                 // och half (uniform per wave)
        const int px_i = (wv >> 1) * 64 + lane;   // 0..255 over 8 g1 rows
        const int lr0 = px_i >> 5;             // g1 local row
        const int x = px_i & 31;
        const int gy = y0 - 2 + lr0;
        const bool inimg = (gy >= 0) && (gy < 32);

        float tap0[9], tap1[9], tap2[9];
#pragma unroll
        for (int dy = 0; dy < 3; ++dy) {
            const int prow = lr0 + dy;         // LDS row for yy = gy+dy-1
#pragma unroll
            for (int dx = 0; dx < 3; ++dx) {
                int xx = x + dx - 1;
                bool rx = (xx >= 0) && (xx < 32);
                tap0[dy * 3 + dx] = rx ? pn_s[prow][xx] : 0.f;
                tap1[dy * 3 + dx] = rx ? pls[prow][xx] : 0.f;
                tap2[dy * 3 + dx] = rx ? prs[prow][xx] : 0.f;
            }
        }
#pragma unroll
        for (int jg = 0; jg < 4; ++jg) {
            u16x8 pk;
#pragma unroll
            for (int e = 0; e < 8; ++e) {
                const int o = oh * 32 + jg * 8 + e;   // uniform per wave
                const float* wr = vrw1 + (size_t)o * 27;
                float acc = vrb1[o];
#pragma unroll
                for (int j = 0; j < 9; ++j) acc = fmaf(tap0[j], wr[j], acc);
#pragma unroll
                for (int j = 0; j < 9; ++j) acc = fmaf(tap1[j], wr[9 + j], acc);
#pragma unroll
                for (int j = 0; j < 9; ++j) acc = fmaf(tap2[j], wr[18 + j], acc);
                pk[e] = f2bf(inimg ? fmaxf(acc, 0.f) : 0.f);
            }
            int byte = (px_i * 128 + oh * 64 + jg * 16) ^ ((px_i & 7) << 4);
            *(u16x8*)((char*)g1_s + byte) = pk;
        }
    }
    __syncthreads();

    // ---- phase C: conv2 (64->64) via MFMA from LDS ------------------------
    {
        const int w = t >> 6, lane = t & 63, q = lane >> 4, l15 = lane & 15;
        const int ocht = w & 3, base = ocht * 16;
        const int wg = w >> 2;                // 0..1

        f32x4 acc[6];
#pragma unroll
        for (int i = 0; i < 6; ++i) acc[i] = f32x4{0.f, 0.f, 0.f, 0.f};

#pragma unroll
        for (int tap = 0; tap < 9; ++tap) {
            const int dy = tap / 3 - 1, dx = tap % 3 - 1;
            const u16* bp = wbv + tap * 4096 + (base + l15) * 64;
            FragU b0 = *(const FragU*)(bp + q * 8);
            FragU b1 = *(const FragU*)(bp + 32 + q * 8);
#pragma unroll
            for (int i = 0; i < 6; ++i) {
                const int p = (wg + 2 * i) * 16 + l15;     // g2 local px 0..191
                const int xx = (p & 31) + dx;
                const int p1 = p + (dy + 1) * 32 + dx;     // g1 local px
                FragU a0, a1;
                if (xx >= 0 && xx < 32) {
                    int byte = (p1 * 128 + q * 16) ^ ((p1 & 7) << 4);
                    a0 = *(const FragU*)((const char*)g1_s + byte);
                    byte = (p1 * 128 + 64 + q * 16) ^ ((p1 & 7) << 4);
                    a1 = *(const FragU*)((const char*)g1_s + byte);
                } else {
#pragma unroll
                    for (int jj = 0; jj < 8; ++jj) { a0.u[jj] = 0; a1.u[jj] = 0; }
                }
                acc[i] = __builtin_amdgcn_mfma_f32_16x16x32_bf16(a0.v, b0.v, acc[i], 0, 0, 0);
                acc[i] = __builtin_amdgcn_mfma_f32_16x16x32_bf16(a1.v, b1.v, acc[i], 0, 0, 0);
            }
        }

        const float bb = vrb2[base + l15];
#pragma unroll
        for (int i = 0; i < 6; ++i) {
#pragma unroll
            for (int e = 0; e < 4; ++e) {
                int p = (wg + 2 * i) * 16 + q * 4 + e;
                int gy2 = y0 - 1 + (p >> 5);
                float vv = (gy2 >= 0 && gy2 < 32) ? fmaxf(acc[i][e] + bb, 0.f) : 0.f;
                int byte = (p * 128 + (base + l15) * 2) ^ ((p & 7) << 4);
                *(u16*)((char*)g2_s + byte) = f2bf(vv);
            }
        }
    }
    __syncthreads();

    // ---- phase D: conv3 (64->1) + residual --------------------------------
    {
        const int px_i = t >> 2;              // 0..127 over 4 out rows
        const int part = t & 3;               // 16-och slice
        const int ly = px_i >> 5;
        const int x  = px_i & 31;

        float a = 0.f;
#pragma unroll
        for (int dy = 0; dy < 3; ++dy) {
#pragma unroll
            for (int dx = 0; dx < 3; ++dx) {
                int xx = x + dx - 1;
                if (xx < 0 || xx >= 32) continue;
                int p2 = px_i + dy * 32 + dx - 1;     // g2 local px
                const int tap = dy * 3 + dx;
                int byte0 = (p2 * 128 + part * 32) ^ ((p2 & 7) << 4);
                int byte1 = (p2 * 128 + part * 32 + 16) ^ ((p2 & 7) << 4);
                u16x8 r0 = *(const u16x8*)((const char*)g2_s + byte0);
                u16x8 r1 = *(const u16x8*)((const char*)g2_s + byte1);
#pragma unroll
                for (int e = 0; e < 8; ++e) {
                    a = fmaf(bf2f(r0[e]), sw3[(part * 16 + e) * 9 + tap], a);
                    a = fmaf(bf2f(r1[e]), sw3[(part * 16 + 8 + e) * 9 + tap], a);
                }
            }
        }
        a += __shfl_xor(a, 1);
        a += __shfl_xor(a, 2);
        if (part == 0) {
            int gy = y0 + ly;
            out[(size_t)m * 1024 + gy * 32 + x] = pn_s[ly + 3][x] + a + vrb3[0];
        }
    }
}

// ---------------- launch ----------------
extern "C" void kernel_launch(void* const* d_in, const int* in_sizes, int n_in,
                              void* d_out, int out_size, void* d_ws, size_t ws_size,
                              hipStream_t stream) {
    const float* lf   = (const float*)d_in[0];
    const float* flow = (const float*)d_in[1];
    const float* wp   = (const float*)d_in[2];
    const float* pl   = (const float*)d_in[3];
    const float* pr   = (const float*)d_in[4];
    float* ws = (float*)d_ws;

    conv1feat_kernel<<<dim3(8, 8, 5), 256, 0, stream>>>(
        flow, lf, wp, (const float*)d_in[5], (const float*)d_in[6],
        (u16*)(ws + X1),
        (const float*)d_in[7], (const float*)d_in[9], (const float*)d_in[21],
        (const float*)d_in[11], (const float*)d_in[13],
        (u16*)(ws + WB2F), (u16*)(ws + WB3F), (u16*)(ws + WBV2),
        (u16*)(ws + W1T), (u16*)(ws + W2T));

    convmfma_kernel<63, 2016, 1><<<dim3(32, 4, 4), 256, 0, stream>>>(
        (const u16*)(ws + X1), (const u16*)(ws + WB2F), (const float*)d_in[8],
        (u16*)(ws + X2));
    convmfma_kernel<63, 2016, 1><<<dim3(32, 4, 4), 256, 0, stream>>>(
        (const u16*)(ws + X2), (const u16*)(ws + WB3F), (const float*)d_in[10],
        (u16*)(ws + FEATBF));

    mlp_mfma_kernel<<<512, 256, 0, stream>>>(
        lf, flow, (const u16*)(ws + FEATBF),
        (const u16*)(ws + W1T), (const u16*)(ws + W2T),
        (const float*)d_in[11], (const float*)d_in[12],
        (const float*)d_in[14],
        (const float*)d_in[15], (const float*)d_in[16],
        (const float*)d_in[17], (const float*)d_in[18],
        ws + NVOFF, ws + CFOFF);

    refine_kernel<<<dim3(8, 14), 512, 0, stream>>>(
        ws + NVOFF, ws + CFOFF, pl, pr,
        (const float*)d_in[19], (const float*)d_in[20],
        (const u16*)(ws + WBV2), (const float*)d_in[22],
        (const float*)d_in[23], (const float*)d_in[24],
        (float*)d_out);
}